// Round 1
// baseline (1035.390 us; speedup 1.0000x reference)
//
#include <hip/hip_runtime.h>

#define SCAN_BLOCK 256
#define SCAN_ITEMS 8
#define SCAN_CHUNK (SCAN_BLOCK * SCAN_ITEMS)  // 2048

// ---------------- degree count ----------------
__global__ __launch_bounds__(256) void k_count(const int* __restrict__ dst,
                                               int* __restrict__ deg, int E) {
    int i = blockIdx.x * blockDim.x + threadIdx.x;
    int stride = gridDim.x * blockDim.x;
    for (int e = i; e < E; e += stride) {
        atomicAdd(&deg[dst[e]], 1);
    }
}

// ---------------- dinv + x*dinv ----------------
__global__ __launch_bounds__(256) void k_dinv(const int* __restrict__ deg,
                                              const float* __restrict__ x,
                                              float* __restrict__ dinv,
                                              float* __restrict__ xd, int n) {
    int i = blockIdx.x * blockDim.x + threadIdx.x;
    if (i >= n) return;
    float d = (float)(deg[i] + 1);   // +1 self loop
    float r = rsqrtf(d);
    dinv[i] = r;
    xd[i] = x[i] * r;
}

// ---------------- prefix scan (3 kernels) ----------------
__global__ __launch_bounds__(SCAN_BLOCK) void k_scan1(const int* __restrict__ deg,
                                                      int* __restrict__ off,
                                                      int* __restrict__ blockSums, int n) {
    __shared__ int lds[SCAN_BLOCK];
    int b = blockIdx.x, t = threadIdx.x;
    int base = b * SCAN_CHUNK + t * SCAN_ITEMS;
    int v[SCAN_ITEMS];
    int sum = 0;
#pragma unroll
    for (int k = 0; k < SCAN_ITEMS; ++k) {
        int idx = base + k;
        v[k] = (idx < n) ? deg[idx] : 0;
        sum += v[k];
    }
    lds[t] = sum;
    __syncthreads();
    for (int d = 1; d < SCAN_BLOCK; d <<= 1) {
        int xval = (t >= d) ? lds[t - d] : 0;
        __syncthreads();
        lds[t] += xval;
        __syncthreads();
    }
    int excl = (t == 0) ? 0 : lds[t - 1];
    if (t == SCAN_BLOCK - 1) blockSums[b] = lds[SCAN_BLOCK - 1];
    int run = excl;
#pragma unroll
    for (int k = 0; k < SCAN_ITEMS; ++k) {
        int idx = base + k;
        if (idx < n) off[idx] = run;
        run += v[k];
    }
}

__global__ __launch_bounds__(256) void k_scan2(int* __restrict__ blockSums, int nb) {
    __shared__ int lds[256];
    int t = threadIdx.x;
    lds[t] = (t < nb) ? blockSums[t] : 0;
    __syncthreads();
    for (int d = 1; d < 256; d <<= 1) {
        int xval = (t >= d) ? lds[t - d] : 0;
        __syncthreads();
        lds[t] += xval;
        __syncthreads();
    }
    int excl = (t == 0) ? 0 : lds[t - 1];
    if (t < nb) blockSums[t] = excl;
}

__global__ __launch_bounds__(SCAN_BLOCK) void k_scan3(int* __restrict__ off,
                                                      int* __restrict__ cursor,
                                                      const int* __restrict__ blockSums, int n) {
    int b = blockIdx.x;
    int add = blockSums[b];
    int base = b * SCAN_CHUNK + threadIdx.x;
#pragma unroll
    for (int k = 0; k < SCAN_ITEMS; ++k) {
        int idx = base + k * SCAN_BLOCK;
        if (idx < n) {
            int o = off[idx] + add;
            off[idx] = o;
            cursor[idx] = o;
        }
    }
}

// ---------------- CSR placement ----------------
__global__ __launch_bounds__(256) void k_place(const int* __restrict__ src,
                                               const int* __restrict__ dst,
                                               int* __restrict__ cursor,
                                               int* __restrict__ csrSrc, int E) {
    int i = blockIdx.x * blockDim.x + threadIdx.x;
    int stride = gridDim.x * blockDim.x;
    for (int e = i; e < E; e += stride) {
        int d = dst[e];
        int slot = atomicAdd(&cursor[d], 1);
        csrSrc[slot] = src[e];
    }
}

// ---------------- layer 1: scalar aggregate + node transform -> t[N][16] ----------------
// t[i][k] = dinv[i] * sum_j relu(W1[j]*s[i]+b1[j]) * W2[j][k]
// s[i]    = dinv[i] * (sum_{e:dst=i} xd[src] + xd[i])
__global__ __launch_bounds__(256) void k_layer1(const int* __restrict__ csrOff,
                                                const int* __restrict__ degc,
                                                const int* __restrict__ csrSrc,
                                                const float* __restrict__ xd,
                                                const float* __restrict__ dinv,
                                                const float* __restrict__ W1,
                                                const float* __restrict__ b1,
                                                const float* __restrict__ W2,
                                                float* __restrict__ t, int n) {
    __shared__ float sW1[16], sb1[16], sW2[256];
    int tid = threadIdx.x;
    if (tid < 16) { sW1[tid] = W1[tid]; sb1[tid] = b1[tid]; }
    sW2[tid] = W2[tid];  // blockDim == 256 == W2 elems, row-major [j][k]
    __syncthreads();

    int lane16 = tid & 15;
    int node = blockIdx.x * 16 + (tid >> 4);
    if (node >= n) return;

    int start = csrOff[node];
    int dcount = degc[node];
    float u = 0.f;
    for (int e = lane16; e < dcount; e += 16) {
        u += xd[csrSrc[start + e]];
    }
#pragma unroll
    for (int d = 1; d < 16; d <<= 1) u += __shfl_xor(u, d, 64);

    float di = dinv[node];
    float s = di * (u + xd[node]);
    float acc = 0.f;
#pragma unroll
    for (int j = 0; j < 16; ++j) {
        float h = fmaxf(fmaf(sW1[j], s, sb1[j]), 0.f);
        acc = fmaf(h, sW2[j * 16 + lane16], acc);
    }
    t[node * 16 + lane16] = acc * di;
}

// ---------------- layer 2: 16-wide aggregate + relu + final projection ----------------
// out[i] = relu(dinv[i]*(sum_e t[src] + t[i]) + b2) . Wl + bl
__global__ __launch_bounds__(256) void k_layer2(const int* __restrict__ csrOff,
                                                const int* __restrict__ degc,
                                                const int* __restrict__ csrSrc,
                                                const float* __restrict__ t,
                                                const float* __restrict__ dinv,
                                                const float* __restrict__ b2,
                                                const float* __restrict__ Wl,
                                                const float* __restrict__ bl,
                                                float* __restrict__ out, int n) {
    int tid = threadIdx.x;
    int lane16 = tid & 15;
    int node = blockIdx.x * 16 + (tid >> 4);
    if (node >= n) return;

    float myB2 = b2[lane16];
    float myWl = Wl[lane16];

    int start = csrOff[node];
    int dcount = degc[node];
    float acc = 0.f;
    for (int e = 0; e < dcount; ++e) {
        int s = csrSrc[start + e];
        acc += t[s * 16 + lane16];
    }
    float di = dinv[node];
    float v = fmaf(di, acc + t[node * 16 + lane16], myB2);
    v = fmaxf(v, 0.f);
    float p = v * myWl;
#pragma unroll
    for (int d = 1; d < 16; d <<= 1) p += __shfl_xor(p, d, 64);
    if (lane16 == 0) out[node] = p + bl[0];
}

extern "C" void kernel_launch(void* const* d_in, const int* in_sizes, int n_in,
                              void* d_out, int out_size, void* d_ws, size_t ws_size,
                              hipStream_t stream) {
    const float* x  = (const float*)d_in[0];
    const int*   ei = (const int*)d_in[1];
    const float* W1 = (const float*)d_in[2];
    const float* b1 = (const float*)d_in[3];
    const float* W2 = (const float*)d_in[4];
    const float* b2 = (const float*)d_in[5];
    const float* Wl = (const float*)d_in[6];
    const float* bl = (const float*)d_in[7];
    float* out = (float*)d_out;

    int n = in_sizes[0];
    int E = in_sizes[1] / 2;
    const int* srcA = ei;
    const int* dstA = ei + E;

    // ---- workspace carve-up (256B aligned) ----
    size_t o = 0;
    auto carve = [&](size_t bytes) {
        void* p = (char*)d_ws + o;
        o = (o + bytes + 255) & ~(size_t)255;
        return p;
    };
    int*   degInt    = (int*)carve((size_t)n * 4);
    float* dinv      = (float*)carve((size_t)n * 4);
    float* xd        = (float*)carve((size_t)n * 4);
    int*   csrOff    = (int*)carve((size_t)n * 4);
    int*   cursor    = (int*)carve((size_t)n * 4);
    int*   blockSums = (int*)carve(1024);
    int*   csrSrc    = (int*)carve((size_t)E * 4);
    float* t         = (float*)carve((size_t)n * 16 * 4);
    (void)ws_size;

    int nb = (n + SCAN_CHUNK - 1) / SCAN_CHUNK;  // 98 for n=200000

    hipMemsetAsync(degInt, 0, (size_t)n * 4, stream);

    k_count<<<2048, 256, 0, stream>>>(dstA, degInt, E);
    k_dinv<<<(n + 255) / 256, 256, 0, stream>>>(degInt, x, dinv, xd, n);
    k_scan1<<<nb, SCAN_BLOCK, 0, stream>>>(degInt, csrOff, blockSums, n);
    k_scan2<<<1, 256, 0, stream>>>(blockSums, nb);
    k_scan3<<<nb, SCAN_BLOCK, 0, stream>>>(csrOff, cursor, blockSums, n);
    k_place<<<2048, 256, 0, stream>>>(srcA, dstA, cursor, csrSrc, E);

    int nodeBlocks = (n + 15) / 16;
    k_layer1<<<nodeBlocks, 256, 0, stream>>>(csrOff, degInt, csrSrc, xd, dinv,
                                             W1, b1, W2, t, n);
    k_layer2<<<nodeBlocks, 256, 0, stream>>>(csrOff, degInt, csrSrc, t, dinv,
                                             b2, Wl, bl, out, n);
}

// Round 2
// 284.167 us; speedup vs baseline: 3.6436x; 3.6436x over previous
//
#include <hip/hip_runtime.h>

#define NBMAX 256
#define BSHIFT 10
#define BW 1024
#define CHUNK 4096

// ---------------- pass B1: bucket histogram ----------------
__global__ __launch_bounds__(256) void k_bhist(const int* __restrict__ dst,
                                               int* __restrict__ bucketCount, int E) {
    __shared__ int h[NBMAX];
    int t = threadIdx.x;
    h[t] = 0;
    __syncthreads();
    int i = blockIdx.x * blockDim.x + t;
    int stride = gridDim.x * blockDim.x;
    for (int e = i; e < E; e += stride)
        atomicAdd(&h[dst[e] >> BSHIFT], 1);
    __syncthreads();
    if (h[t]) atomicAdd(&bucketCount[t], h[t]);
}

// ---------------- bucket scan (1 block) ----------------
__global__ __launch_bounds__(256) void k_bscan(const int* __restrict__ bucketCount,
                                               int* __restrict__ bucketBase,
                                               int* __restrict__ bucketCursor,
                                               int NB, int E) {
    __shared__ int lds[NBMAX];
    int t = threadIdx.x;
    lds[t] = (t < NB) ? bucketCount[t] : 0;
    __syncthreads();
    for (int d = 1; d < NBMAX; d <<= 1) {
        int v = (t >= d) ? lds[t - d] : 0;
        __syncthreads();
        lds[t] += v;
        __syncthreads();
    }
    int excl = (t == 0) ? 0 : lds[t - 1];
    if (t < NB) { bucketBase[t] = excl; bucketCursor[t] = excl; }
    if (t == 0) bucketBase[NB] = E;
}

// ---------------- pass B2: block counting-sort by bucket, coalesced flush ----------------
__global__ __launch_bounds__(256) void k_bin(const int* __restrict__ src,
                                             const int* __restrict__ dst,
                                             int* __restrict__ bucketCursor,
                                             unsigned int* __restrict__ binned, int E) {
    __shared__ int hist[NBMAX];
    __shared__ int excl[NBMAX];
    __shared__ int cur[NBMAX];
    __shared__ int gbase[NBMAX];
    __shared__ unsigned int vals[CHUNK];
    __shared__ unsigned char bkt[CHUNK];
    int t = threadIdx.x;
    int base = blockIdx.x * CHUNK;
    int cnt = min(CHUNK, E - base);
    hist[t] = 0;
    __syncthreads();
    for (int k = t; k < cnt; k += 256)
        atomicAdd(&hist[dst[base + k] >> BSHIFT], 1);
    __syncthreads();
    int hv = hist[t];
    excl[t] = hv;
    __syncthreads();
    for (int d = 1; d < NBMAX; d <<= 1) {
        int v = (t >= d) ? excl[t - d] : 0;
        __syncthreads();
        excl[t] += v;
        __syncthreads();
    }
    int ex = excl[t] - hv;   // exclusive local offset
    __syncthreads();
    excl[t] = ex;
    cur[t] = ex;
    if (hv) gbase[t] = atomicAdd(&bucketCursor[t], hv);
    __syncthreads();
    for (int k = t; k < cnt; k += 256) {
        int d = dst[base + k];
        int b = d >> BSHIFT;
        int r = atomicAdd(&cur[b], 1);
        vals[r] = ((unsigned int)src[base + k] << BSHIFT) | (unsigned int)(d & (BW - 1));
        bkt[r] = (unsigned char)b;
    }
    __syncthreads();
    for (int s = t; s < cnt; s += 256) {
        int b = bkt[s];
        binned[gbase[b] + (s - excl[b])] = vals[s];
    }
}

// ---------------- pass C: per-bucket counting sort -> CSR (+deg/dinv/xd fused) ----------------
__global__ __launch_bounds__(1024) void k_csr(const unsigned int* __restrict__ binned,
                                              const int* __restrict__ bucketBase,
                                              const float* __restrict__ x,
                                              int* __restrict__ csrOff,
                                              int* __restrict__ deg,
                                              float* __restrict__ dinv,
                                              float* __restrict__ xd,
                                              int* __restrict__ csrSrc, int n) {
    __shared__ int cA[BW];
    __shared__ int cB[BW];
    int t = threadIdx.x;
    int b = blockIdx.x;
    int nodeBase = b << BSHIFT;
    int nNodes = min(BW, n - nodeBase);
    int ebase = bucketBase[b];
    int ecnt = bucketBase[b + 1] - ebase;
    cA[t] = 0;
    __syncthreads();
    for (int i = t; i < ecnt; i += 1024)
        atomicAdd(&cA[binned[ebase + i] & (BW - 1)], 1);
    __syncthreads();
    int c = cA[t];
    cB[t] = c;
    __syncthreads();
    for (int d = 1; d < BW; d <<= 1) {
        int v = (t >= d) ? cB[t - d] : 0;
        __syncthreads();
        cB[t] += v;
        __syncthreads();
    }
    int ex = cB[t] - c;
    __syncthreads();
    cA[t] = ex;  // per-node cursor
    if (t < nNodes) {
        int node = nodeBase + t;
        csrOff[node] = ebase + ex;
        deg[node] = c;
        float r = rsqrtf((float)(c + 1));
        dinv[node] = r;
        xd[node] = x[node] * r;
    }
    __syncthreads();
    for (int i = t; i < ecnt; i += 1024) {
        unsigned int v = binned[ebase + i];
        int dl = v & (BW - 1);
        int r = atomicAdd(&cA[dl], 1);
        csrSrc[ebase + r] = (int)(v >> BSHIFT);
    }
}

// ---------------- layer 1: scalar aggregate + node transform -> t[N][16] ----------------
__global__ __launch_bounds__(256) void k_layer1(const int* __restrict__ csrOff,
                                                const int* __restrict__ degc,
                                                const int* __restrict__ csrSrc,
                                                const float* __restrict__ xd,
                                                const float* __restrict__ dinv,
                                                const float* __restrict__ W1,
                                                const float* __restrict__ b1,
                                                const float* __restrict__ W2,
                                                float* __restrict__ t, int n) {
    __shared__ float sW1[16], sb1[16], sW2[256];
    int tid = threadIdx.x;
    if (tid < 16) { sW1[tid] = W1[tid]; sb1[tid] = b1[tid]; }
    sW2[tid] = W2[tid];
    __syncthreads();

    int lane16 = tid & 15;
    int node = blockIdx.x * 16 + (tid >> 4);
    if (node >= n) return;

    int start = csrOff[node];
    int dcount = degc[node];
    float u = 0.f;
    for (int e = lane16; e < dcount; e += 16)
        u += xd[csrSrc[start + e]];
#pragma unroll
    for (int d = 1; d < 16; d <<= 1) u += __shfl_xor(u, d, 64);

    float di = dinv[node];
    float s = di * (u + xd[node]);
    float acc = 0.f;
#pragma unroll
    for (int j = 0; j < 16; ++j) {
        float h = fmaxf(fmaf(sW1[j], s, sb1[j]), 0.f);
        acc = fmaf(h, sW2[j * 16 + lane16], acc);
    }
    t[node * 16 + lane16] = acc * di;
}

// ---------------- layer 2: 16-wide aggregate + relu + final projection ----------------
__global__ __launch_bounds__(256) void k_layer2(const int* __restrict__ csrOff,
                                                const int* __restrict__ degc,
                                                const int* __restrict__ csrSrc,
                                                const float* __restrict__ t,
                                                const float* __restrict__ dinv,
                                                const float* __restrict__ b2,
                                                const float* __restrict__ Wl,
                                                const float* __restrict__ bl,
                                                float* __restrict__ out, int n) {
    int tid = threadIdx.x;
    int lane16 = tid & 15;
    int node = blockIdx.x * 16 + (tid >> 4);
    if (node >= n) return;

    float myB2 = b2[lane16];
    float myWl = Wl[lane16];

    int start = csrOff[node];
    int dcount = degc[node];
    float acc = 0.f;
    int e = 0;
    for (; e + 4 <= dcount; e += 4) {
        int s0 = csrSrc[start + e];
        int s1 = csrSrc[start + e + 1];
        int s2 = csrSrc[start + e + 2];
        int s3 = csrSrc[start + e + 3];
        float a0 = t[s0 * 16 + lane16];
        float a1 = t[s1 * 16 + lane16];
        float a2 = t[s2 * 16 + lane16];
        float a3 = t[s3 * 16 + lane16];
        acc += (a0 + a1) + (a2 + a3);
    }
    for (; e < dcount; ++e)
        acc += t[csrSrc[start + e] * 16 + lane16];

    float di = dinv[node];
    float v = fmaf(di, acc + t[node * 16 + lane16], myB2);
    v = fmaxf(v, 0.f);
    float p = v * myWl;
#pragma unroll
    for (int d = 1; d < 16; d <<= 1) p += __shfl_xor(p, d, 64);
    if (lane16 == 0) out[node] = p + bl[0];
}

extern "C" void kernel_launch(void* const* d_in, const int* in_sizes, int n_in,
                              void* d_out, int out_size, void* d_ws, size_t ws_size,
                              hipStream_t stream) {
    const float* x  = (const float*)d_in[0];
    const int*   ei = (const int*)d_in[1];
    const float* W1 = (const float*)d_in[2];
    const float* b1 = (const float*)d_in[3];
    const float* W2 = (const float*)d_in[4];
    const float* b2 = (const float*)d_in[5];
    const float* Wl = (const float*)d_in[6];
    const float* bl = (const float*)d_in[7];
    float* out = (float*)d_out;

    int n = in_sizes[0];
    int E = in_sizes[1] / 2;
    const int* srcA = ei;
    const int* dstA = ei + E;
    int NB = (n + BW - 1) >> BSHIFT;  // 196 for n=200000

    // ---- workspace carve-up (256B aligned) ----
    size_t o = 0;
    auto carve = [&](size_t bytes) {
        void* p = (char*)d_ws + o;
        o = (o + bytes + 255) & ~(size_t)255;
        return p;
    };
    int*   bucketCount  = (int*)carve(NBMAX * 4);
    int*   bucketBase   = (int*)carve((NBMAX + 1) * 4);
    int*   bucketCursor = (int*)carve(NBMAX * 4);
    int*   csrOff       = (int*)carve((size_t)n * 4);
    int*   deg          = (int*)carve((size_t)n * 4);
    float* dinv         = (float*)carve((size_t)n * 4);
    float* xd           = (float*)carve((size_t)n * 4);
    int*   csrSrc       = (int*)carve((size_t)E * 4);
    unsigned int* binned = (unsigned int*)carve((size_t)E * 4);
    float* t = (float*)binned;  // alias: binned dead after k_csr, t needs n*16*4 <= E*4
    (void)ws_size;

    hipMemsetAsync(bucketCount, 0, NBMAX * 4, stream);

    k_bhist<<<512, 256, 0, stream>>>(dstA, bucketCount, E);
    k_bscan<<<1, 256, 0, stream>>>(bucketCount, bucketBase, bucketCursor, NB, E);
    k_bin<<<(E + CHUNK - 1) / CHUNK, 256, 0, stream>>>(srcA, dstA, bucketCursor, binned, E);
    k_csr<<<NB, 1024, 0, stream>>>(binned, bucketBase, x, csrOff, deg, dinv, xd, csrSrc, n);

    int nodeBlocks = (n + 15) / 16;
    k_layer1<<<nodeBlocks, 256, 0, stream>>>(csrOff, deg, csrSrc, xd, dinv, W1, b1, W2, t, n);
    k_layer2<<<nodeBlocks, 256, 0, stream>>>(csrOff, deg, csrSrc, t, dinv, b2, Wl, bl, out, n);
}